// Round 1
// baseline (639.539 us; speedup 1.0000x reference)
//
#include <hip/hip_runtime.h>

// SE(3) Frechet mean + geodesic variance.
// Layout: one 32-lane group per batch element, one lane per sample (N=32).
// Sample matrices live in registers; cross-sample mean via shfl_xor butterfly.

__device__ __forceinline__ void cross3(const float a[3], const float b[3], float o[3]) {
    o[0] = a[1]*b[2] - a[2]*b[1];
    o[1] = a[2]*b[0] - a[0]*b[2];
    o[2] = a[0]*b[1] - a[1]*b[0];
}

// xi = log_se3([Rr | tr]) ; Rr row-major 3x3.
__device__ __forceinline__ void log_se3_dev(const float Rr[9], const float tr_[3], float xi[6]) {
    float trace = Rr[0] + Rr[4] + Rr[8];
    float ct = (trace - 1.0f) * 0.5f;
    ct = fminf(fmaxf(ct, -0.9999999f), 0.9999999f);
    float theta = acosf(ct);
    float th2 = theta * theta;
    float s_t = __sinf(theta);
    float coeff = theta / (2.0f * s_t);               // theta >= 4.47e-4 due to clip
    float w[3] = { coeff * (Rr[7] - Rr[5]),
                   coeff * (Rr[2] - Rr[6]),
                   coeff * (Rr[3] - Rr[1]) };
    // c = (1 - theta*sin/(2(1-cos)))/th2 ; ill-conditioned for small theta -> series
    float c_t = __cosf(theta);
    float closed = (1.0f - theta * s_t / (2.0f * (1.0f - c_t))) / th2;
    float series = 1.0f/12.0f + th2 * (1.0f/720.0f) + th2*th2*(1.0f/30240.0f);
    float cc = (th2 < 0.01f) ? series : closed;
    float wxt[3], wwxt[3];
    cross3(w, tr_, wxt);
    cross3(w, wxt, wwxt);
    xi[0] = tr_[0] - 0.5f*wxt[0] + cc*wwxt[0];
    xi[1] = tr_[1] - 0.5f*wxt[1] + cc*wwxt[1];
    xi[2] = tr_[2] - 0.5f*wxt[2] + cc*wwxt[2];
    xi[3] = w[0]; xi[4] = w[1]; xi[5] = w[2];
}

__global__ __launch_bounds__(256)
void frechet_se3_kernel(const float* __restrict__ samples,
                        const int* __restrict__ n_iter_p,
                        float* __restrict__ out, int B)
{
    const int lane = threadIdx.x & 63;
    const int sub  = lane & 31;                 // sample index within group
    const int grp  = threadIdx.x >> 5;          // 8 groups (elements) per 256-thread block
    const long bb  = (long)blockIdx.x * 8 + grp;
    if (bb >= B) return;
    const size_t b = (size_t)bb;

    // Load this lane's sample (rows 0..2 of the 4x4; bottom row is [0,0,0,1]).
    const float* sp = samples + ((size_t)sub * (size_t)B + b) * 16;
    float4 a0 = *(const float4*)(sp + 0);
    float4 a1 = *(const float4*)(sp + 4);
    float4 a2 = *(const float4*)(sp + 8);
    float sR[9] = {a0.x,a0.y,a0.z, a1.x,a1.y,a1.z, a2.x,a2.y,a2.z};
    float sT[3] = {a0.w, a1.w, a2.w};

    // mean = samples[0, b]  (all 32 lanes load the same line -> cache broadcast)
    const float* mp = samples + b * 16;
    float4 m0 = *(const float4*)(mp + 0);
    float4 m1 = *(const float4*)(mp + 4);
    float4 m2 = *(const float4*)(mp + 8);
    float mR[9] = {m0.x,m0.y,m0.z, m1.x,m1.y,m1.z, m2.x,m2.y,m2.z};
    float mt[3] = {m0.w, m1.w, m2.w};

    const int ni = *n_iter_p;

    for (int it = 0; it < ni; ++it) {
        // rel = inv(mean) * sample : Rr = mR^T * sR ; tr = mR^T * (sT - mt)
        float dt0 = sT[0]-mt[0], dt1 = sT[1]-mt[1], dt2 = sT[2]-mt[2];
        float Rr[9], tr_[3];
        #pragma unroll
        for (int r = 0; r < 3; ++r) {
            #pragma unroll
            for (int c = 0; c < 3; ++c)
                Rr[r*3+c] = mR[0+r]*sR[0+c] + mR[3+r]*sR[3+c] + mR[6+r]*sR[6+c];
            tr_[r] = mR[0+r]*dt0 + mR[3+r]*dt1 + mR[6+r]*dt2;
        }
        float xi[6];
        log_se3_dev(Rr, tr_, xi);

        // delta = mean over the 32 samples (butterfly within 32-lane halves)
        float delta[6];
        #pragma unroll
        for (int i = 0; i < 6; ++i) {
            float s = xi[i];
            s += __shfl_xor(s, 1);
            s += __shfl_xor(s, 2);
            s += __shfl_xor(s, 4);
            s += __shfl_xor(s, 8);
            s += __shfl_xor(s, 16);
            delta[i] = s * (1.0f/32.0f);
        }

        // exp_se3(delta) — computed redundantly by all lanes (uniform per group)
        float w0 = delta[3], w1 = delta[4], w2 = delta[5];
        float th2 = w0*w0 + w1*w1 + w2*w2;
        bool sm = th2 < 0.01f;
        float st2 = sm ? 1.0f : th2;
        float st = sqrtf(st2);
        float s_ = __sinf(st), c_ = __cosf(st);
        float th4 = th2*th2;
        float A  = sm ? (1.0f - th2*(1.0f/6.0f)  + th4*(1.0f/120.0f))  : (s_/st);
        float Bc = sm ? (0.5f - th2*(1.0f/24.0f) + th4*(1.0f/720.0f))  : ((1.0f-c_)/st2);
        float Cc = sm ? (1.0f/6.0f - th2*(1.0f/120.0f) + th4*(1.0f/5040.0f)) : ((st-s_)/(st2*st));
        float dgn = 1.0f - Bc*th2;   // R = I + A*W + Bc*W^2, W^2 = w w^T - th2 I
        float Re[9] = {
            dgn + Bc*w0*w0,  Bc*w0*w1 - A*w2, Bc*w0*w2 + A*w1,
            Bc*w0*w1 + A*w2, dgn + Bc*w1*w1,  Bc*w1*w2 - A*w0,
            Bc*w0*w2 - A*w1, Bc*w1*w2 + A*w0, dgn + Bc*w2*w2 };
        float rd[3] = {delta[0], delta[1], delta[2]};
        float om[3] = {w0, w1, w2};
        float oxr[3], ooxr[3];
        cross3(om, rd, oxr);
        cross3(om, oxr, ooxr);
        float te0 = rd[0] + Bc*oxr[0] + Cc*ooxr[0];
        float te1 = rd[1] + Bc*oxr[1] + Cc*ooxr[1];
        float te2 = rd[2] + Bc*oxr[2] + Cc*ooxr[2];

        // mean = mean * exp_se3(delta)
        float nR[9], nt[3];
        #pragma unroll
        for (int r = 0; r < 3; ++r) {
            #pragma unroll
            for (int c = 0; c < 3; ++c)
                nR[r*3+c] = mR[r*3+0]*Re[0+c] + mR[r*3+1]*Re[3+c] + mR[r*3+2]*Re[6+c];
            nt[r] = mR[r*3+0]*te0 + mR[r*3+1]*te1 + mR[r*3+2]*te2 + mt[r];
        }
        #pragma unroll
        for (int i = 0; i < 9; ++i) mR[i] = nR[i];
        mt[0]=nt[0]; mt[1]=nt[1]; mt[2]=nt[2];
    }

    // Final pass: geodesic distance^2 per sample, mean over samples.
    {
        float dt0 = sT[0]-mt[0], dt1 = sT[1]-mt[1], dt2 = sT[2]-mt[2];
        float Rr[9], tr_[3];
        #pragma unroll
        for (int r = 0; r < 3; ++r) {
            #pragma unroll
            for (int c = 0; c < 3; ++c)
                Rr[r*3+c] = mR[0+r]*sR[0+c] + mR[3+r]*sR[3+c] + mR[6+r]*sR[6+c];
            tr_[r] = mR[0+r]*dt0 + mR[3+r]*dt1 + mR[6+r]*dt2;
        }
        float xi[6];
        log_se3_dev(Rr, tr_, xi);
        float d2 = xi[0]*xi[0] + xi[1]*xi[1] + xi[2]*xi[2]
                 + xi[3]*xi[3] + xi[4]*xi[4] + xi[5]*xi[5] + 1e-12f;
        float s = d2;
        s += __shfl_xor(s, 1);
        s += __shfl_xor(s, 2);
        s += __shfl_xor(s, 4);
        s += __shfl_xor(s, 8);
        s += __shfl_xor(s, 16);
        if (sub == 0) out[b] = s * (1.0f/32.0f);
    }

    // Write mean (4x4): lanes 0..3 each write one row as float4.
    if (sub < 4) {
        int r = sub;
        float o0 = (r==0)?mR[0]:(r==1)?mR[3]:(r==2)?mR[6]:0.0f;
        float o1 = (r==0)?mR[1]:(r==1)?mR[4]:(r==2)?mR[7]:0.0f;
        float o2 = (r==0)?mR[2]:(r==1)?mR[5]:(r==2)?mR[8]:0.0f;
        float o3 = (r==0)?mt[0]:(r==1)?mt[1]:(r==2)?mt[2]:1.0f;
        *(float4*)(out + (size_t)B + b*16 + (size_t)r*4) = make_float4(o0,o1,o2,o3);
    }
}

extern "C" void kernel_launch(void* const* d_in, const int* in_sizes, int n_in,
                              void* d_out, int out_size, void* d_ws, size_t ws_size,
                              hipStream_t stream) {
    const float* samples = (const float*)d_in[0];
    const int*   n_iter  = (const int*)d_in[1];
    float* out = (float*)d_out;
    const int N = 32;
    int B = in_sizes[0] / (N * 16);
    int blocks = (B + 7) / 8;    // 8 elements (32-lane groups) per 256-thread block
    frechet_se3_kernel<<<blocks, 256, 0, stream>>>(samples, n_iter, out, B);
}

// Round 3
// 601.961 us; speedup vs baseline: 1.0624x; 1.0624x over previous
//
#include <hip/hip_runtime.h>

// SE(3) Frechet mean + geodesic variance.
// Layout: one 32-lane group per batch element, one lane per sample (N=32).
// Sample matrices live in registers; cross-sample mean via DPP/swizzle butterfly.
// All divides/sqrt/acos replaced by raw-rate instructions (v_rcp, v_sqrt, poly):
// without -ffast-math, fp32 "/" is a ~10-instr div_scale/fmas/fixup sequence and
// libm acosf is ~25 instr — we are VALU-issue-bound (VALUBusy ~101% in R1).

__device__ __forceinline__ float frcp(float x)  { return __builtin_amdgcn_rcpf(x); }
__device__ __forceinline__ float fsqrt_(float x){ return __builtin_amdgcn_sqrtf(x); }

// acos via A&S 4.4.46 (7-term, |err| <= 2e-8 rad): acos(x)=sqrt(1-x)*P(x), x>=0.
__device__ __forceinline__ float acos_fast(float x) {
    float ax = fabsf(x);
    float p = fmaf(ax, -0.0012624911f, 0.0066700901f);
    p = fmaf(p, ax, -0.0170881256f);
    p = fmaf(p, ax,  0.0308918810f);
    p = fmaf(p, ax, -0.0501743046f);
    p = fmaf(p, ax,  0.0889789874f);
    p = fmaf(p, ax, -0.2145988016f);
    p = fmaf(p, ax,  1.5707963050f);
    float r = p * fsqrt_(1.0f - ax);
    return (x >= 0.0f) ? r : (3.14159265358979f - r);
}

// Sum over the 32-lane group (two independent groups per wave64).
// xor1, xor2: quad_perm DPP (fused v_add_dpp, full-rate VALU)
// xor8: row_ror:8 DPP (a 16-lane row rotated by 8 == lane^8)
// xor4, xor16: ds_swizzle (BitMode offsets 0x101F / 0x401F)
__device__ __forceinline__ float bfly_sum32(float v) {
    int t;
    t = __builtin_amdgcn_update_dpp(0, __float_as_int(v), 0xB1,  0xF, 0xF, true);
    v += __int_as_float(t);
    t = __builtin_amdgcn_update_dpp(0, __float_as_int(v), 0x4E,  0xF, 0xF, true);
    v += __int_as_float(t);
    t = __builtin_amdgcn_update_dpp(0, __float_as_int(v), 0x128, 0xF, 0xF, true);
    v += __int_as_float(t);
    v += __int_as_float(__builtin_amdgcn_ds_swizzle(__float_as_int(v), 0x101F));
    v += __int_as_float(__builtin_amdgcn_ds_swizzle(__float_as_int(v), 0x401F));
    return v;
}

__device__ __forceinline__ void cross3(const float a[3], const float b[3], float o[3]) {
    o[0] = a[1]*b[2] - a[2]*b[1];
    o[1] = a[2]*b[0] - a[0]*b[2];
    o[2] = a[0]*b[1] - a[1]*b[0];
}

// xi = log_se3([Rr | tr]) ; Rr row-major 3x3.
__device__ __forceinline__ void log_se3_dev(const float Rr[9], const float tr_[3], float xi[6]) {
    float trace = Rr[0] + Rr[4] + Rr[8];
    float ct = (trace - 1.0f) * 0.5f;
    ct = fminf(fmaxf(ct, -0.9999999f), 0.9999999f);
    float theta = acos_fast(ct);
    float th2 = theta * theta;
    // sin(theta) = sqrt((1-ct)(1+ct))  — no v_sin needed; ct-clip keeps it >= ~4.5e-4
    float omc = 1.0f - ct;                      // 1 - cos(theta)
    float s_t = fsqrt_(omc * (1.0f + ct));
    float coeff = theta * frcp(s_t + s_t);      // theta / (2 sin)
    float w[3] = { coeff * (Rr[7] - Rr[5]),
                   coeff * (Rr[2] - Rr[6]),
                   coeff * (Rr[3] - Rr[1]) };
    // c = (1 - theta*sin/(2(1-cos)))/th2 ; ill-conditioned small-theta -> series
    float closed = (1.0f - theta * s_t * frcp(omc + omc)) * frcp(th2);
    float series = 1.0f/12.0f + th2 * (1.0f/720.0f) + th2*th2*(1.0f/30240.0f);
    float cc = (th2 < 0.01f) ? series : closed;
    float wxt[3], wwxt[3];
    cross3(w, tr_, wxt);
    cross3(w, wxt, wwxt);
    xi[0] = tr_[0] - 0.5f*wxt[0] + cc*wwxt[0];
    xi[1] = tr_[1] - 0.5f*wxt[1] + cc*wwxt[1];
    xi[2] = tr_[2] - 0.5f*wxt[2] + cc*wwxt[2];
    xi[3] = w[0]; xi[4] = w[1]; xi[5] = w[2];
}

__global__ __launch_bounds__(256)
void frechet_se3_kernel(const float* __restrict__ samples,
                        const int* __restrict__ n_iter_p,
                        float* __restrict__ out, int B)
{
    const int lane = threadIdx.x & 63;
    const int sub  = lane & 31;                 // sample index within group
    const int grp  = threadIdx.x >> 5;          // 8 groups (elements) per 256-thread block
    const long bb  = (long)blockIdx.x * 8 + grp;
    if (bb >= B) return;
    const size_t b = (size_t)bb;

    // Load this lane's sample (rows 0..2 of the 4x4; bottom row is [0,0,0,1]).
    const float* sp = samples + ((size_t)sub * (size_t)B + b) * 16;
    float4 a0 = *(const float4*)(sp + 0);
    float4 a1 = *(const float4*)(sp + 4);
    float4 a2 = *(const float4*)(sp + 8);
    float sR[9] = {a0.x,a0.y,a0.z, a1.x,a1.y,a1.z, a2.x,a2.y,a2.z};
    float sT[3] = {a0.w, a1.w, a2.w};

    // mean = samples[0, b]  (all 32 lanes load the same line -> cache broadcast)
    const float* mp = samples + b * 16;
    float4 m0 = *(const float4*)(mp + 0);
    float4 m1 = *(const float4*)(mp + 4);
    float4 m2 = *(const float4*)(mp + 8);
    float mR[9] = {m0.x,m0.y,m0.z, m1.x,m1.y,m1.z, m2.x,m2.y,m2.z};
    float mt[3] = {m0.w, m1.w, m2.w};

    const int ni = *n_iter_p;

    for (int it = 0; it < ni; ++it) {
        // rel = inv(mean) * sample : Rr = mR^T * sR ; tr = mR^T * (sT - mt)
        float dt0 = sT[0]-mt[0], dt1 = sT[1]-mt[1], dt2 = sT[2]-mt[2];
        float Rr[9], tr_[3];
        #pragma unroll
        for (int r = 0; r < 3; ++r) {
            #pragma unroll
            for (int c = 0; c < 3; ++c)
                Rr[r*3+c] = mR[0+r]*sR[0+c] + mR[3+r]*sR[3+c] + mR[6+r]*sR[6+c];
            tr_[r] = mR[0+r]*dt0 + mR[3+r]*dt1 + mR[6+r]*dt2;
        }
        float xi[6];
        log_se3_dev(Rr, tr_, xi);

        // delta = mean over the 32 samples
        float delta[6];
        #pragma unroll
        for (int i = 0; i < 6; ++i)
            delta[i] = bfly_sum32(xi[i]) * (1.0f/32.0f);

        // exp_se3(delta) — computed redundantly by all lanes (uniform per group)
        float w0 = delta[3], w1 = delta[4], w2 = delta[5];
        float th2 = w0*w0 + w1*w1 + w2*w2;
        bool sm = th2 < 0.01f;
        float st = fsqrt_(th2);
        float s_ = __sinf(st), c_ = __cosf(st);
        float th4 = th2*th2;
        // one rcp serves A, Bc, Cc on the closed path: r3 = 1/theta^3
        float r3 = frcp(th2 * st);
        float A  = sm ? (1.0f - th2*(1.0f/6.0f)  + th4*(1.0f/120.0f))  : (s_ * th2 * r3);
        float Bc = sm ? (0.5f - th2*(1.0f/24.0f) + th4*(1.0f/720.0f))  : ((1.0f - c_) * st * r3);
        float Cc = sm ? (1.0f/6.0f - th2*(1.0f/120.0f) + th4*(1.0f/5040.0f)) : ((st - s_) * r3);
        float dgn = 1.0f - Bc*th2;   // R = I + A*W + Bc*W^2, W^2 = w w^T - th2 I
        float Re[9] = {
            dgn + Bc*w0*w0,  Bc*w0*w1 - A*w2, Bc*w0*w2 + A*w1,
            Bc*w0*w1 + A*w2, dgn + Bc*w1*w1,  Bc*w1*w2 - A*w0,
            Bc*w0*w2 - A*w1, Bc*w1*w2 + A*w0, dgn + Bc*w2*w2 };
        float rd[3] = {delta[0], delta[1], delta[2]};
        float om[3] = {w0, w1, w2};
        float oxr[3], ooxr[3];
        cross3(om, rd, oxr);
        cross3(om, oxr, ooxr);
        float te0 = rd[0] + Bc*oxr[0] + Cc*ooxr[0];
        float te1 = rd[1] + Bc*oxr[1] + Cc*ooxr[1];
        float te2 = rd[2] + Bc*oxr[2] + Cc*ooxr[2];

        // mean = mean * exp_se3(delta)
        float nR[9], nt[3];
        #pragma unroll
        for (int r = 0; r < 3; ++r) {
            #pragma unroll
            for (int c = 0; c < 3; ++c)
                nR[r*3+c] = mR[r*3+0]*Re[0+c] + mR[r*3+1]*Re[3+c] + mR[r*3+2]*Re[6+c];
            nt[r] = mR[r*3+0]*te0 + mR[r*3+1]*te1 + mR[r*3+2]*te2 + mt[r];
        }
        #pragma unroll
        for (int i = 0; i < 9; ++i) mR[i] = nR[i];
        mt[0]=nt[0]; mt[1]=nt[1]; mt[2]=nt[2];
    }

    // Final pass: geodesic distance^2 per sample, mean over samples.
    {
        float dt0 = sT[0]-mt[0], dt1 = sT[1]-mt[1], dt2 = sT[2]-mt[2];
        float Rr[9], tr_[3];
        #pragma unroll
        for (int r = 0; r < 3; ++r) {
            #pragma unroll
            for (int c = 0; c < 3; ++c)
                Rr[r*3+c] = mR[0+r]*sR[0+c] + mR[3+r]*sR[3+c] + mR[6+r]*sR[6+c];
            tr_[r] = mR[0+r]*dt0 + mR[3+r]*dt1 + mR[6+r]*dt2;
        }
        float xi[6];
        log_se3_dev(Rr, tr_, xi);
        float d2 = xi[0]*xi[0] + xi[1]*xi[1] + xi[2]*xi[2]
                 + xi[3]*xi[3] + xi[4]*xi[4] + xi[5]*xi[5] + 1e-12f;
        float s = bfly_sum32(d2);
        if (sub == 0) out[b] = s * (1.0f/32.0f);
    }

    // Write mean (4x4): lanes 0..3 each write one row as float4.
    if (sub < 4) {
        int r = sub;
        float o0 = (r==0)?mR[0]:(r==1)?mR[3]:(r==2)?mR[6]:0.0f;
        float o1 = (r==0)?mR[1]:(r==1)?mR[4]:(r==2)?mR[7]:0.0f;
        float o2 = (r==0)?mR[2]:(r==1)?mR[5]:(r==2)?mR[8]:0.0f;
        float o3 = (r==0)?mt[0]:(r==1)?mt[1]:(r==2)?mt[2]:1.0f;
        *(float4*)(out + (size_t)B + b*16 + (size_t)r*4) = make_float4(o0,o1,o2,o3);
    }
}

extern "C" void kernel_launch(void* const* d_in, const int* in_sizes, int n_in,
                              void* d_out, int out_size, void* d_ws, size_t ws_size,
                              hipStream_t stream) {
    const float* samples = (const float*)d_in[0];
    const int*   n_iter  = (const int*)d_in[1];
    float* out = (float*)d_out;
    const int N = 32;
    int B = in_sizes[0] / (N * 16);
    int blocks = (B + 7) / 8;    // 8 elements (32-lane groups) per 256-thread block
    frechet_se3_kernel<<<blocks, 256, 0, stream>>>(samples, n_iter, out, B);
}